// Round 14
// baseline (198.347 us; speedup 1.0000x reference)
//
#include <hip/hip_runtime.h>
#include <math.h>

// GCN 2-layer. Radix-partition CSR build; XCD-pinned SLAB-sliced aggregation:
// intermediates stored as contiguous feature slabs (h1: 8 slabs x [N][8] fp16,
// h2: 4 slabs x [N][8] fp16). Agg block (nb, s) with s = blockIdx%8 pins each
// 1.6MB slab to one XCD's L2 -> gather source L2-resident; 16B row per lane
// -> 64 lines in flight per wave instruction. GEMM1/GEMM2 on MFMA.
// out = Anorm( relu(Anorm(x@W1)+b1) @ W2 ) + b2,  Anorm = D^-1/2 (A+I) D^-1/2.

#define THREADS 256
#define HTHREADS 512   // hist/partition block size
#define ATHREADS 512   // aggregation block size (8 waves)
#define PBLK 512       // partition blocks (k_colsum sums 2 rows/thread)
#define BSHIFT 8       // bucket = dst >> 8 (256 nodes/bucket)
#define AGG_NODES 128  // nodes per aggregation block
#define CSR_LDS 3072   // staged csr entries budget (mean 2048, sigma ~45)

typedef _Float16 h8v __attribute__((ext_vector_type(8)));
typedef _Float16 h4v __attribute__((ext_vector_type(4)));
typedef float f32x4 __attribute__((ext_vector_type(4)));

__device__ __forceinline__ int nt_ld_i(const int* p) {
    return __builtin_nontemporal_load(p);
}

__device__ __forceinline__ h8v shfl_xor_h8(h8v v, int off) {
    union { h8v h; int i[4]; } u, r;
    u.h = v;
#pragma unroll
    for (int k = 0; k < 4; ++k) r.i[k] = __shfl_xor(u.i[k], off);
    return r.h;
}

// block-local int64-layout detection (consistent across blocks: same data)
__device__ __forceinline__ int detect64_block(const int* __restrict__ idx, int E,
                                              int* s_flag) {
    if (threadIdx.x == 0) *s_flag = 1;
    __syncthreads();
    int n = (E < 1024) ? E : 1024;
    for (int i = threadIdx.x; i < n; i += blockDim.x)
        if (idx[2 * i + 1] != 0) *s_flag = 0;  // benign race, only 0 written
    __syncthreads();
    return *s_flag;
}

// ---------------- per-block bucket histogram (+ inline detection) ----------------
__global__ __launch_bounds__(HTHREADS) void k_hist(const int* __restrict__ idx, int E,
                                                   int* __restrict__ bh, int NB) {
    extern __shared__ int lh[];  // NB + 1
    int is64 = detect64_block(idx, E, &lh[NB]);
    for (int t = threadIdx.x; t < NB; t += HTHREADS) lh[t] = 0;
    __syncthreads();
    int chunk = (E + PBLK - 1) / PBLK;
    int start = blockIdx.x * chunk;
    int end = min(start + chunk, E);
    for (int e = start + threadIdx.x; e < end; e += HTHREADS) {
        int d = is64 ? idx[2 * E + 2 * e] : idx[E + e];
        atomicAdd(&lh[d >> BSHIFT], 1);
    }
    __syncthreads();
    for (int t = threadIdx.x; t < NB; t += HTHREADS)
        bh[blockIdx.x * NB + t] = lh[t];
}

// ---------------- bucket totals: one block per bucket (PBLK = 2*THREADS) ----------------
__global__ __launch_bounds__(THREADS) void k_colsum(const int* __restrict__ bh,
                                                    int* __restrict__ bcnt, int NB) {
    __shared__ int ws[4];
    int b = blockIdx.x;
    int v = bh[threadIdx.x * NB + b] + bh[(threadIdx.x + THREADS) * NB + b];
    int lane = threadIdx.x & 63, w = threadIdx.x >> 6;
#pragma unroll
    for (int o = 32; o; o >>= 1) v += __shfl_down(v, o);
    if (lane == 0) ws[w] = v;
    __syncthreads();
    if (threadIdx.x == 0) bcnt[b] = ws[0] + ws[1] + ws[2] + ws[3];
}

// ---------------- exclusive scan of bucket totals (1 block) ----------------
__global__ __launch_bounds__(THREADS) void k_scan(const int* __restrict__ cnt,
                                                  int* __restrict__ off, int NB) {
    __shared__ int wsum[4];
    __shared__ int carry_s;
    if (threadIdx.x == 0) carry_s = 0;
    __syncthreads();
    int t = threadIdx.x, lane = t & 63, w = t >> 6;
    for (int base = 0; base < NB; base += THREADS) {
        int i = base + t;
        int raw = (i < NB) ? cnt[i] : 0;
        int v = raw;
#pragma unroll
        for (int o = 1; o < 64; o <<= 1) {
            int u = __shfl_up(v, o);
            if (lane >= o) v += u;
        }
        if (lane == 63) wsum[w] = v;
        __syncthreads();
        int c0 = carry_s;
        int wadd = 0;
#pragma unroll
        for (int k = 0; k < 4; ++k) if (k < w) wadd += wsum[k];
        if (i < NB) off[i] = v - raw + wadd + c0;
        __syncthreads();
        if (t == 0) carry_s += wsum[0] + wsum[1] + wsum[2] + wsum[3];
        __syncthreads();
    }
    if (t == 0) off[NB] = carry_s;  // == E
}

// ---------------- per-(block,bucket) bases: one wave per bucket ----------------
__global__ __launch_bounds__(64) void k_bbase(const int* __restrict__ bh,
                                              const int* __restrict__ boff,
                                              int* __restrict__ bbase, int NB) {
    int b = blockIdx.x;
    int lane = threadIdx.x;
    int carry = boff[b];
    for (int base = 0; base < PBLK; base += 64) {
        int idx = (base + lane) * NB + b;
        int raw = bh[idx];
        int v = raw;
#pragma unroll
        for (int o = 1; o < 64; o <<= 1) {
            int u = __shfl_up(v, o);
            if (lane >= o) v += u;
        }
        bbase[idx] = carry + v - raw;
        carry += __shfl(v, 63);
    }
}

// ---------------- partition: packed (ldst<<24)|src into bucket ranges ----------------
// requires src < 2^24 (N = 100K here)
__global__ __launch_bounds__(HTHREADS) void k_partition(const int* __restrict__ idx, int E,
                                                        const int* __restrict__ bbase,
                                                        unsigned* __restrict__ pairs, int NB) {
    extern __shared__ int sm[];
    int* lbase = sm;        // NB
    int* lcur  = sm + NB;   // NB (+1 for flag)
    int is64 = detect64_block(idx, E, &lcur[NB]);
    for (int t = threadIdx.x; t < NB; t += HTHREADS) {
        lbase[t] = bbase[blockIdx.x * NB + t];
        lcur[t] = 0;
    }
    __syncthreads();
    int chunk = (E + PBLK - 1) / PBLK;
    int start = blockIdx.x * chunk;
    int end = min(start + chunk, E);
    for (int e = start + threadIdx.x; e < end; e += HTHREADS) {
        int s = is64 ? idx[2 * e] : idx[e];
        int d = is64 ? idx[2 * E + 2 * e] : idx[E + e];
        int b = d >> BSHIFT;
        int r = atomicAdd(&lcur[b], 1);
        pairs[lbase[b] + r] = (unsigned)s | ((unsigned)(d & 255) << 24);
    }
}

// ---------------- per-bucket counting sort -> csr_src, row_ptr, dinv ----------------
__global__ __launch_bounds__(THREADS) void k_sort(const unsigned* __restrict__ pairs,
                                                  const int* __restrict__ boff,
                                                  int* __restrict__ csr_src,
                                                  int* __restrict__ row_ptr,
                                                  float* __restrict__ dinv, int N, int NB) {
    __shared__ int cnt[256];
    __shared__ int cur[256];
    __shared__ int wsum[4];
    const int b = blockIdx.x, t = threadIdx.x;
    const int start = boff[b], end = boff[b + 1];
    cnt[t] = 0;
    __syncthreads();
    for (int j = start + t; j < end; j += THREADS)
        atomicAdd(&cnt[pairs[j] >> 24], 1);
    __syncthreads();
    int deg = cnt[t];
    int lane = t & 63, w = t >> 6;
    int v = deg;
#pragma unroll
    for (int o = 1; o < 64; o <<= 1) {
        int u = __shfl_up(v, o);
        if (lane >= o) v += u;
    }
    if (lane == 63) wsum[w] = v;
    __syncthreads();
    int wadd = 0;
#pragma unroll
    for (int k = 0; k < 4; ++k) if (k < w) wadd += wsum[k];
    int pos = start + (v - deg) + wadd;
    cur[t] = pos;
    int node = (b << BSHIFT) + t;
    if (node < N) {
        row_ptr[node] = pos;
        dinv[node] = rsqrtf((float)(deg + 1));  // +1 self loop
    }
    if (b == NB - 1 && t == 0) row_ptr[N] = end;
    __syncthreads();
    for (int j = start + t; j < end; j += THREADS) {
        unsigned p = pairs[j];
        int r = atomicAdd(&cur[p >> 24], 1);
        csr_src[r] = (int)(p & 0xFFFFFFu);
    }
}

// ---------------- GEMM1 (MFMA): h1slab[s][row][8] = fp16(dinv*(x@W1)) ----------------
__global__ __launch_bounds__(THREADS) void k_gemm1(const float* __restrict__ x,
                                                   const float* __restrict__ W,
                                                   const float* __restrict__ dinv,
                                                   _Float16* __restrict__ h, int N) {
    __shared__ _Float16 xs[64][136];   // [row][k], +8 pad
    __shared__ _Float16 wsT[64][136];  // [col][k], transposed W1
    const int tid = threadIdx.x;
    const int brow = blockIdx.x * 64;
    for (int f = tid; f < 64 * 32; f += THREADS) {
        int r = f >> 5, c4 = (f & 31) << 2;
        int row = brow + r;
        float4 v = make_float4(0.f, 0.f, 0.f, 0.f);
        if (row < N) v = *(const float4*)&x[(size_t)row * 128 + c4];
        h4v hv;
        hv.x = (_Float16)v.x; hv.y = (_Float16)v.y;
        hv.z = (_Float16)v.z; hv.w = (_Float16)v.w;
        *(h4v*)&xs[r][c4] = hv;
    }
    for (int f = tid; f < 128 * 16; f += THREADS) {
        int k = f >> 4, n4 = (f & 15) << 2;
        float4 w = *(const float4*)&W[(size_t)k * 64 + n4];
        wsT[n4 + 0][k] = (_Float16)w.x;
        wsT[n4 + 1][k] = (_Float16)w.y;
        wsT[n4 + 2][k] = (_Float16)w.z;
        wsT[n4 + 3][k] = (_Float16)w.w;
    }
    __syncthreads();
    const int wv = tid >> 6, lane = tid & 63;
    const int fr = lane & 15;
    const int kg = lane >> 4;
    f32x4 acc[4];
    acc[0] = acc[1] = acc[2] = acc[3] = (f32x4){0.f, 0.f, 0.f, 0.f};
#pragma unroll
    for (int ks = 0; ks < 4; ++ks) {
        h8v a = *(const h8v*)&xs[(wv << 4) + fr][(kg << 3) + (ks << 5)];
#pragma unroll
        for (int c = 0; c < 4; ++c) {
            h8v b = *(const h8v*)&wsT[(c << 4) + fr][(kg << 3) + (ks << 5)];
            acc[c] = __builtin_amdgcn_mfma_f32_16x16x32_f16(a, b, acc[c], 0, 0, 0);
        }
    }
#pragma unroll
    for (int i = 0; i < 4; ++i) {
        int row = brow + (wv << 4) + (kg << 2) + i;
        if (row < N) {
            float dn = dinv[row];
#pragma unroll
            for (int c = 0; c < 4; ++c) {
                int col = (c << 4) + fr;
                // slab layout: h[(slab*N + row)*8 + (col&7)]
                h[((size_t)(col >> 3) * N + row) * 8 + (col & 7)] =
                    (_Float16)(acc[c][i] * dn);
            }
        }
    }
}

// ---------------- layer-1 slab agg: block (nb, s=bid%8); 4 lanes/node ----------------
// Each lane loads full 16B slab rows (64 lines in flight / wave instr);
// 2-level packed shfl reduce; o1slab = fp16(relu(dinv*(sum+self)+b1_slice)).
__global__ __launch_bounds__(ATHREADS) void k_agg1s(const int* __restrict__ row_ptr,
                                                    const int* __restrict__ csr,
                                                    const float* __restrict__ dinv,
                                                    const _Float16* __restrict__ hs,
                                                    const float* __restrict__ b1,
                                                    _Float16* __restrict__ o1, int N) {
    __shared__ int rp_s[AGG_NODES + 1];
    __shared__ float dinv_s[AGG_NODES];
    __shared__ int csr_s[CSR_LDS];  // 12KB
    const int tid = threadIdx.x;
    const int s = blockIdx.x & 7;
    const int nbase = (blockIdx.x >> 3) * AGG_NODES;
    const int nend = min(nbase + AGG_NODES, N);
    const int ncnt = nend - nbase;
    if (tid <= ncnt) rp_s[tid] = row_ptr[nbase + tid];
    if (tid < ncnt) dinv_s[tid] = dinv[nbase + tid];
    __syncthreads();
    const int seg0 = rp_s[0];
    const int seglen = rp_s[ncnt] - seg0;
    const bool inlds = (seglen <= CSR_LDS);
    if (inlds)
        for (int t = tid; t < seglen; t += ATHREADS) csr_s[t] = nt_ld_i(&csr[seg0 + t]);
    __syncthreads();

    const _Float16* hslab = hs + (size_t)s * N * 8;
    const int wv = tid >> 6, lane = tid & 63;
    const int g = lane >> 2, fl = lane & 3;

    const int nloc = (wv << 4) + g;
    const bool act = (nloc < ncnt);
    const int node = nbase + nloc;
    const int start = act ? rp_s[nloc] : 0;
    const int end = act ? rp_s[nloc + 1] : 0;
    h8v a0 = {0, 0, 0, 0, 0, 0, 0, 0};
    h8v a1 = a0;
    if (act && fl == 0) a0 = *(const h8v*)&hslab[(size_t)node * 8];  // self row
    if (inlds) {
        int j = start - seg0 + fl;
        const int e_ = end - seg0;
        for (; j + 4 < e_; j += 8) {
            int s0 = csr_s[j], s1 = csr_s[j + 4];
            a0 += *(const h8v*)&hslab[(size_t)s0 * 8];
            a1 += *(const h8v*)&hslab[(size_t)s1 * 8];
        }
        if (j < e_) a0 += *(const h8v*)&hslab[(size_t)csr_s[j] * 8];
    } else {
        int j = start + fl;
        for (; j + 4 < end; j += 8) {
            int s0 = nt_ld_i(&csr[j]), s1 = nt_ld_i(&csr[j + 4]);
            a0 += *(const h8v*)&hslab[(size_t)s0 * 8];
            a1 += *(const h8v*)&hslab[(size_t)s1 * 8];
        }
        if (j < end) a0 += *(const h8v*)&hslab[(size_t)nt_ld_i(&csr[j]) * 8];
    }
    a0 += a1;
    a0 += shfl_xor_h8(a0, 1);
    a0 += shfl_xor_h8(a0, 2);
    if (act && fl == 0) {
        const float dn = dinv_s[nloc];
        const int fb = s << 3;
        float4 bb0 = *(const float4*)&b1[fb];
        float4 bb1 = *(const float4*)&b1[fb + 4];
        h8v o;
        o[0] = (_Float16)fmaxf(dn * (float)a0[0] + bb0.x, 0.f);
        o[1] = (_Float16)fmaxf(dn * (float)a0[1] + bb0.y, 0.f);
        o[2] = (_Float16)fmaxf(dn * (float)a0[2] + bb0.z, 0.f);
        o[3] = (_Float16)fmaxf(dn * (float)a0[3] + bb0.w, 0.f);
        o[4] = (_Float16)fmaxf(dn * (float)a0[4] + bb1.x, 0.f);
        o[5] = (_Float16)fmaxf(dn * (float)a0[5] + bb1.y, 0.f);
        o[6] = (_Float16)fmaxf(dn * (float)a0[6] + bb1.z, 0.f);
        o[7] = (_Float16)fmaxf(dn * (float)a0[7] + bb1.w, 0.f);
        *(h8v*)&o1[((size_t)s * N + node) * 8] = o;
    }
}

// ---------------- GEMM2 (MFMA): h2slab[c>>3][row][8] = fp16(dinv*(o1@W2)) ----------------
// [N,64]@[64,32]; block 128 rows, 4 waves, wave = 32 rows (2 row-tiles x 2 col-tiles).
__global__ __launch_bounds__(THREADS) void k_gemm2(const _Float16* __restrict__ o1,
                                                   const float* __restrict__ W,
                                                   const float* __restrict__ dinv,
                                                   _Float16* __restrict__ h2, int N) {
    __shared__ _Float16 xs[128][72];  // [row][k], +8 pad (18.4KB)
    __shared__ _Float16 wsT[32][72];  // [col][k] (4.6KB)
    const int tid = threadIdx.x;
    const int brow = blockIdx.x * 128;
    // stage o1 slabs -> xs (rows fastest within slab => coalesced 16B loads)
    for (int f = tid; f < 1024; f += THREADS) {
        int s = f >> 7, row = f & 127;
        h8v v = {0, 0, 0, 0, 0, 0, 0, 0};
        if (brow + row < N) v = *(const h8v*)&o1[((size_t)s * N + brow + row) * 8];
        *(h8v*)&xs[row][s << 3] = v;
    }
    for (int f = tid; f < 64 * 32; f += THREADS) {
        int k = f >> 5, c = f & 31;
        wsT[c][k] = (_Float16)W[(size_t)k * 32 + c];
    }
    __syncthreads();
    const int wv = tid >> 6, lane = tid & 63;
    const int fr = lane & 15;
    const int kg = lane >> 4;
    f32x4 acc[2][2];
    acc[0][0] = acc[0][1] = acc[1][0] = acc[1][1] = (f32x4){0.f, 0.f, 0.f, 0.f};
#pragma unroll
    for (int rt = 0; rt < 2; ++rt) {
#pragma unroll
        for (int ks = 0; ks < 2; ++ks) {
            h8v a = *(const h8v*)&xs[(wv << 5) + (rt << 4) + fr][(kg << 3) + (ks << 5)];
#pragma unroll
            for (int ct = 0; ct < 2; ++ct) {
                h8v b = *(const h8v*)&wsT[(ct << 4) + fr][(kg << 3) + (ks << 5)];
                acc[rt][ct] = __builtin_amdgcn_mfma_f32_16x16x32_f16(a, b, acc[rt][ct], 0, 0, 0);
            }
        }
    }
#pragma unroll
    for (int rt = 0; rt < 2; ++rt) {
#pragma unroll
        for (int i = 0; i < 4; ++i) {
            int row = brow + (wv << 5) + (rt << 4) + (kg << 2) + i;
            if (row < N) {
                float dn = dinv[row];
#pragma unroll
                for (int ct = 0; ct < 2; ++ct) {
                    int col = (ct << 4) + fr;
                    h2[((size_t)(col >> 3) * N + row) * 8 + (col & 7)] =
                        (_Float16)(acc[rt][ct][i] * dn);
                }
            }
        }
    }
}

// ---------------- layer-2 slab agg: block (nb, s=bid%4); 4 lanes/node ----------------
// slice s -> XCDs {s, s+4} (grid = nb*4+s, %8 round-robin). out = fp32 final.
__global__ __launch_bounds__(ATHREADS) void k_agg2s(const int* __restrict__ row_ptr,
                                                    const int* __restrict__ csr,
                                                    const float* __restrict__ dinv,
                                                    const _Float16* __restrict__ hs,
                                                    const float* __restrict__ b2,
                                                    float* __restrict__ out, int N) {
    __shared__ int rp_s[AGG_NODES + 1];
    __shared__ float dinv_s[AGG_NODES];
    __shared__ int csr_s[CSR_LDS];
    const int tid = threadIdx.x;
    const int s = blockIdx.x & 3;
    const int nbase = (blockIdx.x >> 2) * AGG_NODES;
    const int nend = min(nbase + AGG_NODES, N);
    const int ncnt = nend - nbase;
    if (tid <= ncnt) rp_s[tid] = row_ptr[nbase + tid];
    if (tid < ncnt) dinv_s[tid] = dinv[nbase + tid];
    __syncthreads();
    const int seg0 = rp_s[0];
    const int seglen = rp_s[ncnt] - seg0;
    const bool inlds = (seglen <= CSR_LDS);
    if (inlds)
        for (int t = tid; t < seglen; t += ATHREADS) csr_s[t] = nt_ld_i(&csr[seg0 + t]);
    __syncthreads();

    const _Float16* hslab = hs + (size_t)s * N * 8;
    const int wv = tid >> 6, lane = tid & 63;
    const int g = lane >> 2, fl = lane & 3;

    const int nloc = (wv << 4) + g;
    const bool act = (nloc < ncnt);
    const int node = nbase + nloc;
    const int start = act ? rp_s[nloc] : 0;
    const int end = act ? rp_s[nloc + 1] : 0;
    h8v a0 = {0, 0, 0, 0, 0, 0, 0, 0};
    h8v a1 = a0;
    if (act && fl == 0) a0 = *(const h8v*)&hslab[(size_t)node * 8];  // self row
    if (inlds) {
        int j = start - seg0 + fl;
        const int e_ = end - seg0;
        for (; j + 4 < e_; j += 8) {
            int s0 = csr_s[j], s1 = csr_s[j + 4];
            a0 += *(const h8v*)&hslab[(size_t)s0 * 8];
            a1 += *(const h8v*)&hslab[(size_t)s1 * 8];
        }
        if (j < e_) a0 += *(const h8v*)&hslab[(size_t)csr_s[j] * 8];
    } else {
        int j = start + fl;
        for (; j + 4 < end; j += 8) {
            int s0 = nt_ld_i(&csr[j]), s1 = nt_ld_i(&csr[j + 4]);
            a0 += *(const h8v*)&hslab[(size_t)s0 * 8];
            a1 += *(const h8v*)&hslab[(size_t)s1 * 8];
        }
        if (j < end) a0 += *(const h8v*)&hslab[(size_t)nt_ld_i(&csr[j]) * 8];
    }
    a0 += a1;
    a0 += shfl_xor_h8(a0, 1);
    a0 += shfl_xor_h8(a0, 2);
    if (act && fl == 0) {
        const float dn = dinv_s[nloc];
        const int fb = s << 3;
        float4 bb0 = *(const float4*)&b2[fb];
        float4 bb1 = *(const float4*)&b2[fb + 4];
        float4 r0, r1;
        r0.x = dn * (float)a0[0] + bb0.x;
        r0.y = dn * (float)a0[1] + bb0.y;
        r0.z = dn * (float)a0[2] + bb0.z;
        r0.w = dn * (float)a0[3] + bb0.w;
        r1.x = dn * (float)a0[4] + bb1.x;
        r1.y = dn * (float)a0[5] + bb1.y;
        r1.z = dn * (float)a0[6] + bb1.z;
        r1.w = dn * (float)a0[7] + bb1.w;
        *(float4*)&out[(size_t)node * 32 + fb] = r0;
        *(float4*)&out[(size_t)node * 32 + fb + 4] = r1;
    }
}

extern "C" void kernel_launch(void* const* d_in, const int* in_sizes, int n_in,
                              void* d_out, int out_size, void* d_ws, size_t ws_size,
                              hipStream_t stream) {
    const int N = in_sizes[0] / 128;
    const int E = in_sizes[1] / 2;
    const float* x  = (const float*)d_in[0];
    const int*   ei = (const int*)d_in[1];
    const float* W1 = (const float*)d_in[2];
    const float* b1 = (const float*)d_in[3];
    const float* W2 = (const float*)d_in[4];
    const float* b2 = (const float*)d_in[5];
    float* out = (float*)d_out;

    const int NB = (N + 255) >> BSHIFT;

    // workspace carve. pairs aliases h1b (dead until k_gemm1, after k_sort;
    // E*4B = 6.4MB <= N*64*2B = 12.8MB).
    float*     dinv    = (float*)d_ws;                    // N
    _Float16*  h1b     = (_Float16*)(dinv + N);           // 8 slabs x N x 8 fp16
    _Float16*  o1b     = h1b + (size_t)N * 64;            // 8 slabs x N x 8 fp16
    _Float16*  h2b     = o1b + (size_t)N * 64;            // 4 slabs x N x 8 fp16
    int*       csr_src = (int*)(h2b + (size_t)N * 32);    // E
    int*       row_ptr = csr_src + E;                     // N+1
    int*       bh      = row_ptr + N + 1;                 // PBLK*NB
    int*       bbase   = bh + (size_t)PBLK * NB;          // PBLK*NB
    int*       bcnt    = bbase + (size_t)PBLK * NB;       // NB
    int*       boff    = bcnt + NB;                       // NB+1
    unsigned*  pairs   = (unsigned*)h1b;                  // E (aliased)

    k_hist<<<PBLK, HTHREADS, (NB + 1) * 4, stream>>>(ei, E, bh, NB);
    k_colsum<<<NB, THREADS, 0, stream>>>(bh, bcnt, NB);
    k_scan<<<1, THREADS, 0, stream>>>(bcnt, boff, NB);
    k_bbase<<<NB, 64, 0, stream>>>(bh, boff, bbase, NB);
    k_partition<<<PBLK, HTHREADS, (2 * NB + 1) * 4, stream>>>(ei, E, bbase, pairs, NB);
    k_sort<<<NB, THREADS, 0, stream>>>(pairs, boff, csr_src, row_ptr, dinv, N, NB);

    k_gemm1<<<(N + 63) / 64, THREADS, 0, stream>>>(x, W1, dinv, h1b, N);
    const int nb128 = (N + AGG_NODES - 1) / AGG_NODES;
    k_agg1s<<<nb128 * 8, ATHREADS, 0, stream>>>(row_ptr, csr_src, dinv, h1b, b1, o1b, N);
    k_gemm2<<<nb128, THREADS, 0, stream>>>(o1b, W2, dinv, h2b, N);
    k_agg2s<<<nb128 * 4, ATHREADS, 0, stream>>>(row_ptr, csr_src, dinv, h2b, b2, out, N);
}

// Round 15
// 130.897 us; speedup vs baseline: 1.5153x; 1.5153x over previous
//
#include <hip/hip_runtime.h>
#include <math.h>

// GCN 2-layer. Radix-partition CSR build; group-per-node gather aggregation
// (block-staged CSR, fp16 rows, 8-deep unrolled packed accumulate); GEMM1 on
// MFMA (fp16 in, fp32 acc); layer-1 agg fused with ReLU + GEMM2 (vectorized).
// out = Anorm( relu(Anorm(x@W1)+b1) @ W2 ) + b2,  Anorm = D^-1/2 (A+I) D^-1/2.

#define THREADS 256
#define HTHREADS 512  // hist/partition block size
#define PBLK 512      // partition blocks (k_colsum sums 2 rows/thread)
#define BSHIFT 8      // bucket = dst >> 8 (256 nodes/bucket)
#define AGG_NODES 64  // nodes per aggregation block
#define CSR_LDS 1536  // staged csr entries budget (mean 1024, sigma 32)

typedef _Float16 h8v __attribute__((ext_vector_type(8)));
typedef _Float16 h4v __attribute__((ext_vector_type(4)));
typedef float f32x4 __attribute__((ext_vector_type(4)));

__device__ __forceinline__ int nt_ld_i(const int* p) {
    return __builtin_nontemporal_load(p);
}

// block-local int64-layout detection (consistent across blocks: same data)
__device__ __forceinline__ int detect64_block(const int* __restrict__ idx, int E,
                                              int* s_flag) {
    if (threadIdx.x == 0) *s_flag = 1;
    __syncthreads();
    int n = (E < 1024) ? E : 1024;
    for (int i = threadIdx.x; i < n; i += blockDim.x)
        if (idx[2 * i + 1] != 0) *s_flag = 0;  // benign race, only 0 written
    __syncthreads();
    return *s_flag;
}

// ---------------- per-block bucket histogram (+ inline detection) ----------------
__global__ __launch_bounds__(HTHREADS) void k_hist(const int* __restrict__ idx, int E,
                                                   int* __restrict__ bh, int NB) {
    extern __shared__ int lh[];  // NB + 1
    int is64 = detect64_block(idx, E, &lh[NB]);
    for (int t = threadIdx.x; t < NB; t += HTHREADS) lh[t] = 0;
    __syncthreads();
    int chunk = (E + PBLK - 1) / PBLK;
    int start = blockIdx.x * chunk;
    int end = min(start + chunk, E);
    for (int e = start + threadIdx.x; e < end; e += HTHREADS) {
        int d = is64 ? idx[2 * E + 2 * e] : idx[E + e];
        atomicAdd(&lh[d >> BSHIFT], 1);
    }
    __syncthreads();
    for (int t = threadIdx.x; t < NB; t += HTHREADS)
        bh[blockIdx.x * NB + t] = lh[t];
}

// ---------------- bucket totals: one block per bucket (PBLK = 2*THREADS) ----------------
__global__ __launch_bounds__(THREADS) void k_colsum(const int* __restrict__ bh,
                                                    int* __restrict__ bcnt, int NB) {
    __shared__ int ws[4];
    int b = blockIdx.x;
    int v = bh[threadIdx.x * NB + b] + bh[(threadIdx.x + THREADS) * NB + b];
    int lane = threadIdx.x & 63, w = threadIdx.x >> 6;
#pragma unroll
    for (int o = 32; o; o >>= 1) v += __shfl_down(v, o);
    if (lane == 0) ws[w] = v;
    __syncthreads();
    if (threadIdx.x == 0) bcnt[b] = ws[0] + ws[1] + ws[2] + ws[3];
}

// ---------------- per-(block,bucket) bases (computes own bucket offset) ----------------
// bbase[k*NB+b] = sum_{i<b} bcnt[i] + sum_{k'<k} bh[k'*NB+b].
// Note bbase[0*NB+b] == bucket b's global start offset.
__global__ __launch_bounds__(64) void k_bbase(const int* __restrict__ bh,
                                              const int* __restrict__ bcnt,
                                              int* __restrict__ bbase, int NB) {
    int b = blockIdx.x;
    int lane = threadIdx.x;
    // boff[b] = exclusive sum of bcnt[0..b)
    int off = 0;
    for (int base = 0; base < b; base += 64) {
        int i = base + lane;
        int v = (i < b) ? bcnt[i] : 0;
#pragma unroll
        for (int o = 32; o; o >>= 1) v += __shfl_down(v, o);
        off += __shfl(v, 0);
    }
    int carry = off;
    for (int base = 0; base < PBLK; base += 64) {
        int idx = (base + lane) * NB + b;
        int raw = bh[idx];
        int v = raw;
#pragma unroll
        for (int o = 1; o < 64; o <<= 1) {
            int u = __shfl_up(v, o);
            if (lane >= o) v += u;
        }
        bbase[idx] = carry + v - raw;
        carry += __shfl(v, 63);
    }
}

// ---------------- partition: packed (ldst<<24)|src into bucket ranges ----------------
// requires src < 2^24 (N = 100K here)
__global__ __launch_bounds__(HTHREADS) void k_partition(const int* __restrict__ idx, int E,
                                                        const int* __restrict__ bbase,
                                                        unsigned* __restrict__ pairs, int NB) {
    extern __shared__ int sm[];
    int* lbase = sm;        // NB
    int* lcur  = sm + NB;   // NB (+1 for flag)
    int is64 = detect64_block(idx, E, &lcur[NB]);
    for (int t = threadIdx.x; t < NB; t += HTHREADS) {
        lbase[t] = bbase[blockIdx.x * NB + t];
        lcur[t] = 0;
    }
    __syncthreads();
    int chunk = (E + PBLK - 1) / PBLK;
    int start = blockIdx.x * chunk;
    int end = min(start + chunk, E);
    for (int e = start + threadIdx.x; e < end; e += HTHREADS) {
        int s = is64 ? idx[2 * e] : idx[e];
        int d = is64 ? idx[2 * E + 2 * e] : idx[E + e];
        int b = d >> BSHIFT;
        int r = atomicAdd(&lcur[b], 1);
        pairs[lbase[b] + r] = (unsigned)s | ((unsigned)(d & 255) << 24);
    }
}

// ---------------- per-bucket counting sort -> csr_src, row_ptr, dinv ----------------
// bucket bounds come from bbase row 0 (bbase[0*NB+b] = bucket start).
__global__ __launch_bounds__(THREADS) void k_sort(const unsigned* __restrict__ pairs,
                                                  const int* __restrict__ bbase,
                                                  int* __restrict__ csr_src,
                                                  int* __restrict__ row_ptr,
                                                  float* __restrict__ dinv,
                                                  int N, int NB, int E) {
    __shared__ int cnt[256];
    __shared__ int cur[256];
    __shared__ int wsum[4];
    const int b = blockIdx.x, t = threadIdx.x;
    const int start = bbase[b];
    const int end = (b + 1 < NB) ? bbase[b + 1] : E;
    cnt[t] = 0;
    __syncthreads();
    for (int j = start + t; j < end; j += THREADS)
        atomicAdd(&cnt[pairs[j] >> 24], 1);
    __syncthreads();
    int deg = cnt[t];
    int lane = t & 63, w = t >> 6;
    int v = deg;
#pragma unroll
    for (int o = 1; o < 64; o <<= 1) {
        int u = __shfl_up(v, o);
        if (lane >= o) v += u;
    }
    if (lane == 63) wsum[w] = v;
    __syncthreads();
    int wadd = 0;
#pragma unroll
    for (int k = 0; k < 4; ++k) if (k < w) wadd += wsum[k];
    int pos = start + (v - deg) + wadd;
    cur[t] = pos;
    int node = (b << BSHIFT) + t;
    if (node < N) {
        row_ptr[node] = pos;
        dinv[node] = rsqrtf((float)(deg + 1));  // +1 self loop
    }
    if (b == NB - 1 && t == 0) row_ptr[N] = end;
    __syncthreads();
    for (int j = start + t; j < end; j += THREADS) {
        unsigned p = pairs[j];
        int r = atomicAdd(&cur[p >> 24], 1);
        csr_src[r] = (int)(p & 0xFFFFFFu);
    }
}

// ---------------- GEMM1 (MFMA): h1h = fp16(dinv[row] * (x @ W1)) ----------------
__global__ __launch_bounds__(THREADS) void k_gemm1(const float* __restrict__ x,
                                                   const float* __restrict__ W,
                                                   const float* __restrict__ dinv,
                                                   _Float16* __restrict__ h, int N) {
    __shared__ _Float16 xs[64][136];   // [row][k], +8 pad
    __shared__ _Float16 wsT[64][136];  // [col][k], transposed W1
    const int tid = threadIdx.x;
    const int brow = blockIdx.x * 64;
    for (int f = tid; f < 64 * 32; f += THREADS) {
        int r = f >> 5, c4 = (f & 31) << 2;
        int row = brow + r;
        float4 v = make_float4(0.f, 0.f, 0.f, 0.f);
        if (row < N) v = *(const float4*)&x[(size_t)row * 128 + c4];
        h4v hv;
        hv.x = (_Float16)v.x; hv.y = (_Float16)v.y;
        hv.z = (_Float16)v.z; hv.w = (_Float16)v.w;
        *(h4v*)&xs[r][c4] = hv;
    }
    for (int f = tid; f < 128 * 16; f += THREADS) {
        int k = f >> 4, n4 = (f & 15) << 2;
        float4 w = *(const float4*)&W[(size_t)k * 64 + n4];
        wsT[n4 + 0][k] = (_Float16)w.x;
        wsT[n4 + 1][k] = (_Float16)w.y;
        wsT[n4 + 2][k] = (_Float16)w.z;
        wsT[n4 + 3][k] = (_Float16)w.w;
    }
    __syncthreads();
    const int wv = tid >> 6, lane = tid & 63;
    const int fr = lane & 15;
    const int kg = lane >> 4;
    f32x4 acc[4];
    acc[0] = acc[1] = acc[2] = acc[3] = (f32x4){0.f, 0.f, 0.f, 0.f};
#pragma unroll
    for (int ks = 0; ks < 4; ++ks) {
        h8v a = *(const h8v*)&xs[(wv << 4) + fr][(kg << 3) + (ks << 5)];
#pragma unroll
        for (int c = 0; c < 4; ++c) {
            h8v b = *(const h8v*)&wsT[(c << 4) + fr][(kg << 3) + (ks << 5)];
            acc[c] = __builtin_amdgcn_mfma_f32_16x16x32_f16(a, b, acc[c], 0, 0, 0);
        }
    }
#pragma unroll
    for (int i = 0; i < 4; ++i) {
        int row = brow + (wv << 4) + (kg << 2) + i;
        if (row < N) {
            float dn = dinv[row];
#pragma unroll
            for (int c = 0; c < 4; ++c)
                h[(size_t)row * 64 + (c << 4) + fr] = (_Float16)(acc[c][i] * dn);
        }
    }
}

// ---------------- fused layer-1 agg + bias + ReLU + GEMM2 (group-per-node, 8 chains) ----------------
__global__ __launch_bounds__(THREADS) void k_agg1f(const int* __restrict__ row_ptr,
                                                   const int* __restrict__ csr,
                                                   const float* __restrict__ dinv,
                                                   const _Float16* __restrict__ hs,
                                                   const float* __restrict__ b1,
                                                   const float* __restrict__ W2,
                                                   _Float16* __restrict__ h2s, int N) {
    __shared__ float w2s[64][32];          // 8KB
    __shared__ float rowbuf[4][8][68];     // 8.5KB, padded
    __shared__ int rp_s[AGG_NODES + 1];
    __shared__ float dinv_s[AGG_NODES];
    __shared__ int csr_s[CSR_LDS];         // 6KB
    const int tid = threadIdx.x;
    for (int f = tid; f < 64 * 8; f += THREADS) {
        int k = f >> 3, c4 = (f & 7) << 2;
        *(float4*)&w2s[k][c4] = *(const float4*)&W2[(size_t)k * 32 + c4];
    }
    const int nbase = blockIdx.x * AGG_NODES;
    const int nend = min(nbase + AGG_NODES, N);
    const int ncnt = nend - nbase;
    if (tid <= ncnt) rp_s[tid] = row_ptr[nbase + tid];
    if (tid < ncnt) dinv_s[tid] = dinv[nbase + tid];
    __syncthreads();
    const int seg0 = rp_s[0];
    const int seglen = rp_s[ncnt] - seg0;
    const bool inlds = (seglen <= CSR_LDS);
    if (inlds)
        for (int t = tid; t < seglen; t += THREADS) csr_s[t] = nt_ld_i(&csr[seg0 + t]);
    __syncthreads();

    const int wv = tid >> 6, lane = tid & 63;
    const int g = lane >> 3, fl = lane & 7;
    const int fb = fl << 3;

    for (int c = 0; c < 2; ++c) {
        const int nloc = (wv << 4) + (c << 3) + g;
        const bool act = (nloc < ncnt);
        const int node = nbase + nloc;
        const int start = act ? rp_s[nloc] : 0;
        const int end = act ? rp_s[nloc + 1] : 0;
        h8v a0 = {0, 0, 0, 0, 0, 0, 0, 0};
        h8v a1 = a0, a2 = a0, a3 = a0, a4 = a0, a5 = a0, a6 = a0, a7 = a0;
        if (act) a0 = *(const h8v*)&hs[(size_t)node * 64 + fb];  // self row
        if (inlds) {
            int j = start - seg0;
            const int e_ = end - seg0;
            for (; j + 7 < e_; j += 8) {
                int s0 = csr_s[j],     s1 = csr_s[j + 1], s2 = csr_s[j + 2], s3 = csr_s[j + 3];
                int s4 = csr_s[j + 4], s5 = csr_s[j + 5], s6 = csr_s[j + 6], s7 = csr_s[j + 7];
                a0 += *(const h8v*)&hs[(size_t)s0 * 64 + fb];
                a1 += *(const h8v*)&hs[(size_t)s1 * 64 + fb];
                a2 += *(const h8v*)&hs[(size_t)s2 * 64 + fb];
                a3 += *(const h8v*)&hs[(size_t)s3 * 64 + fb];
                a4 += *(const h8v*)&hs[(size_t)s4 * 64 + fb];
                a5 += *(const h8v*)&hs[(size_t)s5 * 64 + fb];
                a6 += *(const h8v*)&hs[(size_t)s6 * 64 + fb];
                a7 += *(const h8v*)&hs[(size_t)s7 * 64 + fb];
            }
            int rem = e_ - j;
            if (rem > 0) a1 += *(const h8v*)&hs[(size_t)csr_s[j] * 64 + fb];
            if (rem > 1) a2 += *(const h8v*)&hs[(size_t)csr_s[j + 1] * 64 + fb];
            if (rem > 2) a3 += *(const h8v*)&hs[(size_t)csr_s[j + 2] * 64 + fb];
            if (rem > 3) a4 += *(const h8v*)&hs[(size_t)csr_s[j + 3] * 64 + fb];
            if (rem > 4) a5 += *(const h8v*)&hs[(size_t)csr_s[j + 4] * 64 + fb];
            if (rem > 5) a6 += *(const h8v*)&hs[(size_t)csr_s[j + 5] * 64 + fb];
            if (rem > 6) a7 += *(const h8v*)&hs[(size_t)csr_s[j + 6] * 64 + fb];
        } else {
            int j = start;
            for (; j + 7 < end; j += 8) {
                int s0 = nt_ld_i(&csr[j]),     s1 = nt_ld_i(&csr[j + 1]);
                int s2 = nt_ld_i(&csr[j + 2]), s3 = nt_ld_i(&csr[j + 3]);
                int s4 = nt_ld_i(&csr[j + 4]), s5 = nt_ld_i(&csr[j + 5]);
                int s6 = nt_ld_i(&csr[j + 6]), s7 = nt_ld_i(&csr[j + 7]);
                a0 += *(const h8v*)&hs[(size_t)s0 * 64 + fb];
                a1 += *(const h8v*)&hs[(size_t)s1 * 64 + fb];
                a2 += *(const h8v*)&hs[(size_t)s2 * 64 + fb];
                a3 += *(const h8v*)&hs[(size_t)s3 * 64 + fb];
                a4 += *(const h8v*)&hs[(size_t)s4 * 64 + fb];
                a5 += *(const h8v*)&hs[(size_t)s5 * 64 + fb];
                a6 += *(const h8v*)&hs[(size_t)s6 * 64 + fb];
                a7 += *(const h8v*)&hs[(size_t)s7 * 64 + fb];
            }
            int rem = end - j;
            if (rem > 0) a1 += *(const h8v*)&hs[(size_t)nt_ld_i(&csr[j]) * 64 + fb];
            if (rem > 1) a2 += *(const h8v*)&hs[(size_t)nt_ld_i(&csr[j + 1]) * 64 + fb];
            if (rem > 2) a3 += *(const h8v*)&hs[(size_t)nt_ld_i(&csr[j + 2]) * 64 + fb];
            if (rem > 3) a4 += *(const h8v*)&hs[(size_t)nt_ld_i(&csr[j + 3]) * 64 + fb];
            if (rem > 4) a5 += *(const h8v*)&hs[(size_t)nt_ld_i(&csr[j + 4]) * 64 + fb];
            if (rem > 5) a6 += *(const h8v*)&hs[(size_t)nt_ld_i(&csr[j + 5]) * 64 + fb];
            if (rem > 6) a7 += *(const h8v*)&hs[(size_t)nt_ld_i(&csr[j + 6]) * 64 + fb];
        }
        // fold 8 -> 4 in fp16, then fp32 combine
        a0 += a4; a1 += a5; a2 += a6; a3 += a7;
        if (act) {
            const float dn = dinv_s[nloc];
            float4 bb0 = *(const float4*)&b1[fb];
            float4 bb1 = *(const float4*)&b1[fb + 4];
            float4 r0, r1;
            r0.x = fmaxf(dn * (((float)a0[0] + (float)a1[0]) + ((float)a2[0] + (float)a3[0])) + bb0.x, 0.f);
            r0.y = fmaxf(dn * (((float)a0[1] + (float)a1[1]) + ((float)a2[1] + (float)a3[1])) + bb0.y, 0.f);
            r0.z = fmaxf(dn * (((float)a0[2] + (float)a1[2]) + ((float)a2[2] + (float)a3[2])) + bb0.z, 0.f);
            r0.w = fmaxf(dn * (((float)a0[3] + (float)a1[3]) + ((float)a2[3] + (float)a3[3])) + bb0.w, 0.f);
            r1.x = fmaxf(dn * (((float)a0[4] + (float)a1[4]) + ((float)a2[4] + (float)a3[4])) + bb1.x, 0.f);
            r1.y = fmaxf(dn * (((float)a0[5] + (float)a1[5]) + ((float)a2[5] + (float)a3[5])) + bb1.y, 0.f);
            r1.z = fmaxf(dn * (((float)a0[6] + (float)a1[6]) + ((float)a2[6] + (float)a3[6])) + bb1.z, 0.f);
            r1.w = fmaxf(dn * (((float)a0[7] + (float)a1[7]) + ((float)a2[7] + (float)a3[7])) + bb1.w, 0.f);
            *(float4*)&rowbuf[wv][g][fb] = r0;
            *(float4*)&rowbuf[wv][g][fb + 4] = r1;
        }
        // GEMM2 (vectorized): 4 cols/lane, K=64 in float4 steps
        if (act) {
            float c0 = 0.f, c1 = 0.f, c2 = 0.f, c3 = 0.f;
            const int cb = fl << 2;
#pragma unroll
            for (int k4 = 0; k4 < 64; k4 += 4) {
                float4 r = *(const float4*)&rowbuf[wv][g][k4];
                float4 w0 = *(const float4*)&w2s[k4 + 0][cb];
                float4 w1 = *(const float4*)&w2s[k4 + 1][cb];
                float4 w2 = *(const float4*)&w2s[k4 + 2][cb];
                float4 w3 = *(const float4*)&w2s[k4 + 3][cb];
                c0 += r.x * w0.x + r.y * w1.x + r.z * w2.x + r.w * w3.x;
                c1 += r.x * w0.y + r.y * w1.y + r.z * w2.y + r.w * w3.y;
                c2 += r.x * w0.z + r.y * w1.z + r.z * w2.z + r.w * w3.z;
                c3 += r.x * w0.w + r.y * w1.w + r.z * w2.w + r.w * w3.w;
            }
            const float dn = dinv_s[nloc];
            h4v hv;
            hv.x = (_Float16)(dn * c0);
            hv.y = (_Float16)(dn * c1);
            hv.z = (_Float16)(dn * c2);
            hv.w = (_Float16)(dn * c3);
            *(h4v*)&h2s[(size_t)node * 32 + (fl << 2)] = hv;
        }
    }
}

// ---------------- layer-2 agg (group-per-node, 8 chains): 16 groups x 4 lanes ----------------
__global__ __launch_bounds__(THREADS) void k_agg2(const int* __restrict__ row_ptr,
                                                  const int* __restrict__ csr,
                                                  const float* __restrict__ dinv,
                                                  const _Float16* __restrict__ hs,
                                                  const float* __restrict__ b2,
                                                  float* __restrict__ out, int N) {
    __shared__ int rp_s[AGG_NODES + 1];
    __shared__ float dinv_s[AGG_NODES];
    __shared__ int csr_s[CSR_LDS];
    const int tid = threadIdx.x;
    const int nbase = blockIdx.x * AGG_NODES;
    const int nend = min(nbase + AGG_NODES, N);
    const int ncnt = nend - nbase;
    if (tid <= ncnt) rp_s[tid] = row_ptr[nbase + tid];
    if (tid < ncnt) dinv_s[tid] = dinv[nbase + tid];
    __syncthreads();
    const int seg0 = rp_s[0];
    const int seglen = rp_s[ncnt] - seg0;
    const bool inlds = (seglen <= CSR_LDS);
    if (inlds)
        for (int t = tid; t < seglen; t += THREADS) csr_s[t] = nt_ld_i(&csr[seg0 + t]);
    __syncthreads();

    const int wv = tid >> 6, lane = tid & 63;
    const int g = lane >> 2, fl = lane & 3;
    const int fb = fl << 3;

    const int nloc = (wv << 4) + g;
    const bool act = (nloc < ncnt);
    const int node = nbase + nloc;
    const int start = act ? rp_s[nloc] : 0;
    const int end = act ? rp_s[nloc + 1] : 0;
    h8v a0 = {0, 0, 0, 0, 0, 0, 0, 0};
    h8v a1 = a0, a2 = a0, a3 = a0, a4 = a0, a5 = a0, a6 = a0, a7 = a0;
    if (act) a0 = *(const h8v*)&hs[(size_t)node * 32 + fb];  // self row
    if (inlds) {
        int j = start - seg0;
        const int e_ = end - seg0;
        for (; j + 7 < e_; j += 8) {
            int s0 = csr_s[j],     s1 = csr_s[j + 1], s2 = csr_s[j + 2], s3 = csr_s[j + 3];
            int s4 = csr_s[j + 4], s5 = csr_s[j + 5], s6 = csr_s[j + 6], s7 = csr_s[j + 7];
            a0 += *(const h8v*)&hs[(size_t)s0 * 32 + fb];
            a1 += *(const h8v*)&hs[(size_t)s1 * 32 + fb];
            a2 += *(const h8v*)&hs[(size_t)s2 * 32 + fb];
            a3 += *(const h8v*)&hs[(size_t)s3 * 32 + fb];
            a4 += *(const h8v*)&hs[(size_t)s4 * 32 + fb];
            a5 += *(const h8v*)&hs[(size_t)s5 * 32 + fb];
            a6 += *(const h8v*)&hs[(size_t)s6 * 32 + fb];
            a7 += *(const h8v*)&hs[(size_t)s7 * 32 + fb];
        }
        int rem = e_ - j;
        if (rem > 0) a1 += *(const h8v*)&hs[(size_t)csr_s[j] * 32 + fb];
        if (rem > 1) a2 += *(const h8v*)&hs[(size_t)csr_s[j + 1] * 32 + fb];
        if (rem > 2) a3 += *(const h8v*)&hs[(size_t)csr_s[j + 2] * 32 + fb];
        if (rem > 3) a4 += *(const h8v*)&hs[(size_t)csr_s[j + 3] * 32 + fb];
        if (rem > 4) a5 += *(const h8v*)&hs[(size_t)csr_s[j + 4] * 32 + fb];
        if (rem > 5) a6 += *(const h8v*)&hs[(size_t)csr_s[j + 5] * 32 + fb];
        if (rem > 6) a7 += *(const h8v*)&hs[(size_t)csr_s[j + 6] * 32 + fb];
    } else {
        int j = start;
        for (; j + 7 < end; j += 8) {
            int s0 = nt_ld_i(&csr[j]),     s1 = nt_ld_i(&csr[j + 1]);
            int s2 = nt_ld_i(&csr[j + 2]), s3 = nt_ld_i(&csr[j + 3]);
            int s4 = nt_ld_i(&csr[j + 4]), s5 = nt_ld_i(&csr[j + 5]);
            int s6 = nt_ld_i(&csr[j + 6]), s7 = nt_ld_i(&csr[j + 7]);
            a0 += *(const h8v*)&hs[(size_t)s0 * 32 + fb];
            a1 += *(const h8v*)&hs[(size_t)s1 * 32 + fb];
            a2 += *(const h8v*)&hs[(size_t)s2 * 32 + fb];
            a3 += *(const h8v*)&hs[(size_t)s3 * 32 + fb];
            a4 += *(const h8v*)&hs[(size_t)s4 * 32 + fb];
            a5 += *(const h8v*)&hs[(size_t)s5 * 32 + fb];
            a6 += *(const h8v*)&hs[(size_t)s6 * 32 + fb];
            a7 += *(const h8v*)&hs[(size_t)s7 * 32 + fb];
        }
        int rem = end - j;
        if (rem > 0) a1 += *(const h8v*)&hs[(size_t)nt_ld_i(&csr[j]) * 32 + fb];
        if (rem > 1) a2 += *(const h8v*)&hs[(size_t)nt_ld_i(&csr[j + 1]) * 32 + fb];
        if (rem > 2) a3 += *(const h8v*)&hs[(size_t)nt_ld_i(&csr[j + 2]) * 32 + fb];
        if (rem > 3) a4 += *(const h8v*)&hs[(size_t)nt_ld_i(&csr[j + 3]) * 32 + fb];
        if (rem > 4) a5 += *(const h8v*)&hs[(size_t)nt_ld_i(&csr[j + 4]) * 32 + fb];
        if (rem > 5) a6 += *(const h8v*)&hs[(size_t)nt_ld_i(&csr[j + 5]) * 32 + fb];
        if (rem > 6) a7 += *(const h8v*)&hs[(size_t)nt_ld_i(&csr[j + 6]) * 32 + fb];
    }
    a0 += a4; a1 += a5; a2 += a6; a3 += a7;
    if (act) {
        const float dn = dinv_s[nloc];
        float4 bb0 = *(const float4*)&b2[fb];
        float4 bb1 = *(const float4*)&b2[fb + 4];
        float4 r0, r1;
        r0.x = dn * (((float)a0[0] + (float)a1[0]) + ((float)a2[0] + (float)a3[0])) + bb0.x;
        r0.y = dn * (((float)a0[1] + (float)a1[1]) + ((float)a2[1] + (float)a3[1])) + bb0.y;
        r0.z = dn * (((float)a0[2] + (float)a1[2]) + ((float)a2[2] + (float)a3[2])) + bb0.z;
        r0.w = dn * (((float)a0[3] + (float)a1[3]) + ((float)a2[3] + (float)a3[3])) + bb0.w;
        r1.x = dn * (((float)a0[4] + (float)a1[4]) + ((float)a2[4] + (float)a3[4])) + bb1.x;
        r1.y = dn * (((float)a0[5] + (float)a1[5]) + ((float)a2[5] + (float)a3[5])) + bb1.y;
        r1.z = dn * (((float)a0[6] + (float)a1[6]) + ((float)a2[6] + (float)a3[6])) + bb1.z;
        r1.w = dn * (((float)a0[7] + (float)a1[7]) + ((float)a2[7] + (float)a3[7])) + bb1.w;
        *(float4*)&out[(size_t)node * 32 + fb] = r0;
        *(float4*)&out[(size_t)node * 32 + fb + 4] = r1;
    }
}

extern "C" void kernel_launch(void* const* d_in, const int* in_sizes, int n_in,
                              void* d_out, int out_size, void* d_ws, size_t ws_size,
                              hipStream_t stream) {
    const int N = in_sizes[0] / 128;
    const int E = in_sizes[1] / 2;
    const float* x  = (const float*)d_in[0];
    const int*   ei = (const int*)d_in[1];
    const float* W1 = (const float*)d_in[2];
    const float* b1 = (const float*)d_in[3];
    const float* W2 = (const float*)d_in[4];
    const float* b2 = (const float*)d_in[5];
    float* out = (float*)d_out;

    const int NB = (N + 255) >> BSHIFT;

    // workspace carve. pairs aliases h1b (dead until k_gemm1, which runs after k_sort;
    // E*4B = 6.4MB <= N*64*2B = 12.8MB).
    float*     dinv    = (float*)d_ws;                    // N
    _Float16*  h1b     = (_Float16*)(dinv + N);           // N*64 fp16
    _Float16*  h2b     = h1b + (size_t)N * 64;            // N*32 fp16
    int*       csr_src = (int*)(h2b + (size_t)N * 32);    // E
    int*       row_ptr = csr_src + E;                     // N+1
    int*       bh      = row_ptr + N + 1;                 // PBLK*NB
    int*       bbase   = bh + (size_t)PBLK * NB;          // PBLK*NB
    int*       bcnt    = bbase + (size_t)PBLK * NB;       // NB
    unsigned*  pairs   = (unsigned*)h1b;                  // E (aliased)

    k_hist<<<PBLK, HTHREADS, (NB + 1) * 4, stream>>>(ei, E, bh, NB);
    k_colsum<<<NB, THREADS, 0, stream>>>(bh, bcnt, NB);
    k_bbase<<<NB, 64, 0, stream>>>(bh, bcnt, bbase, NB);
    k_partition<<<PBLK, HTHREADS, (2 * NB + 1) * 4, stream>>>(ei, E, bbase, pairs, NB);
    k_sort<<<NB, THREADS, 0, stream>>>(pairs, bbase, csr_src, row_ptr, dinv, N, NB, E);

    k_gemm1<<<(N + 63) / 64, THREADS, 0, stream>>>(x, W1, dinv, h1b, N);
    const int ablk = (N + AGG_NODES - 1) / AGG_NODES;
    k_agg1f<<<ablk, THREADS, 0, stream>>>(row_ptr, csr_src, dinv, h1b, b1, W2, h2b, N);
    k_agg2<<<ablk, THREADS, 0, stream>>>(row_ptr, csr_src, dinv, h2b, b2, out, N);
}

// Round 16
// 125.677 us; speedup vs baseline: 1.5782x; 1.0415x over previous
//
#include <hip/hip_runtime.h>
#include <math.h>

// GCN 2-layer. Radix-partition CSR build (5 kernels); group-per-node gather
// aggregation (block-staged CSR, fp16 rows, 4-deep unrolled packed
// accumulate); GEMM1 on MFMA (fp16 in, fp32 acc); layer-1 agg fused with
// ReLU + GEMM2 (vectorized).
// out = Anorm( relu(Anorm(x@W1)+b1) @ W2 ) + b2,  Anorm = D^-1/2 (A+I) D^-1/2.
// Best-known config (R11 agg + R14 build): ~126 us.

#define THREADS 256
#define HTHREADS 512  // hist/partition block size
#define PBLK 512      // partition blocks (k_colsum sums 2 rows/thread)
#define BSHIFT 8      // bucket = dst >> 8 (256 nodes/bucket)
#define AGG_NODES 64  // nodes per aggregation block
#define CSR_LDS 1536  // staged csr entries budget (mean 1024, sigma 32)

typedef _Float16 h8v __attribute__((ext_vector_type(8)));
typedef _Float16 h4v __attribute__((ext_vector_type(4)));
typedef float f32x4 __attribute__((ext_vector_type(4)));

__device__ __forceinline__ int nt_ld_i(const int* p) {
    return __builtin_nontemporal_load(p);
}

// block-local int64-layout detection (consistent across blocks: same data)
__device__ __forceinline__ int detect64_block(const int* __restrict__ idx, int E,
                                              int* s_flag) {
    if (threadIdx.x == 0) *s_flag = 1;
    __syncthreads();
    int n = (E < 1024) ? E : 1024;
    for (int i = threadIdx.x; i < n; i += blockDim.x)
        if (idx[2 * i + 1] != 0) *s_flag = 0;  // benign race, only 0 written
    __syncthreads();
    return *s_flag;
}

// ---------------- per-block bucket histogram (+ inline detection) ----------------
__global__ __launch_bounds__(HTHREADS) void k_hist(const int* __restrict__ idx, int E,
                                                   int* __restrict__ bh, int NB) {
    extern __shared__ int lh[];  // NB + 1
    int is64 = detect64_block(idx, E, &lh[NB]);
    for (int t = threadIdx.x; t < NB; t += HTHREADS) lh[t] = 0;
    __syncthreads();
    int chunk = (E + PBLK - 1) / PBLK;
    int start = blockIdx.x * chunk;
    int end = min(start + chunk, E);
    for (int e = start + threadIdx.x; e < end; e += HTHREADS) {
        int d = is64 ? idx[2 * E + 2 * e] : idx[E + e];
        atomicAdd(&lh[d >> BSHIFT], 1);
    }
    __syncthreads();
    for (int t = threadIdx.x; t < NB; t += HTHREADS)
        bh[blockIdx.x * NB + t] = lh[t];
}

// ---------------- bucket totals: one block per bucket (PBLK = 2*THREADS) ----------------
__global__ __launch_bounds__(THREADS) void k_colsum(const int* __restrict__ bh,
                                                    int* __restrict__ bcnt, int NB) {
    __shared__ int ws[4];
    int b = blockIdx.x;
    int v = bh[threadIdx.x * NB + b] + bh[(threadIdx.x + THREADS) * NB + b];
    int lane = threadIdx.x & 63, w = threadIdx.x >> 6;
#pragma unroll
    for (int o = 32; o; o >>= 1) v += __shfl_down(v, o);
    if (lane == 0) ws[w] = v;
    __syncthreads();
    if (threadIdx.x == 0) bcnt[b] = ws[0] + ws[1] + ws[2] + ws[3];
}

// ---------------- per-(block,bucket) bases (computes own bucket offset) ----------------
// bbase[k*NB+b] = sum_{i<b} bcnt[i] + sum_{k'<k} bh[k'*NB+b].
// Note bbase[0*NB+b] == bucket b's global start offset.
__global__ __launch_bounds__(64) void k_bbase(const int* __restrict__ bh,
                                              const int* __restrict__ bcnt,
                                              int* __restrict__ bbase, int NB) {
    int b = blockIdx.x;
    int lane = threadIdx.x;
    // boff[b] = exclusive sum of bcnt[0..b)
    int off = 0;
    for (int base = 0; base < b; base += 64) {
        int i = base + lane;
        int v = (i < b) ? bcnt[i] : 0;
#pragma unroll
        for (int o = 32; o; o >>= 1) v += __shfl_down(v, o);
        off += __shfl(v, 0);
    }
    int carry = off;
    for (int base = 0; base < PBLK; base += 64) {
        int idx = (base + lane) * NB + b;
        int raw = bh[idx];
        int v = raw;
#pragma unroll
        for (int o = 1; o < 64; o <<= 1) {
            int u = __shfl_up(v, o);
            if (lane >= o) v += u;
        }
        bbase[idx] = carry + v - raw;
        carry += __shfl(v, 63);
    }
}

// ---------------- partition: packed (ldst<<24)|src into bucket ranges ----------------
// requires src < 2^24 (N = 100K here)
__global__ __launch_bounds__(HTHREADS) void k_partition(const int* __restrict__ idx, int E,
                                                        const int* __restrict__ bbase,
                                                        unsigned* __restrict__ pairs, int NB) {
    extern __shared__ int sm[];
    int* lbase = sm;        // NB
    int* lcur  = sm + NB;   // NB (+1 for flag)
    int is64 = detect64_block(idx, E, &lcur[NB]);
    for (int t = threadIdx.x; t < NB; t += HTHREADS) {
        lbase[t] = bbase[blockIdx.x * NB + t];
        lcur[t] = 0;
    }
    __syncthreads();
    int chunk = (E + PBLK - 1) / PBLK;
    int start = blockIdx.x * chunk;
    int end = min(start + chunk, E);
    for (int e = start + threadIdx.x; e < end; e += HTHREADS) {
        int s = is64 ? idx[2 * e] : idx[e];
        int d = is64 ? idx[2 * E + 2 * e] : idx[E + e];
        int b = d >> BSHIFT;
        int r = atomicAdd(&lcur[b], 1);
        pairs[lbase[b] + r] = (unsigned)s | ((unsigned)(d & 255) << 24);
    }
}

// ---------------- per-bucket counting sort -> csr_src, row_ptr, dinv ----------------
// bucket bounds come from bbase row 0 (bbase[0*NB+b] = bucket start).
__global__ __launch_bounds__(THREADS) void k_sort(const unsigned* __restrict__ pairs,
                                                  const int* __restrict__ bbase,
                                                  int* __restrict__ csr_src,
                                                  int* __restrict__ row_ptr,
                                                  float* __restrict__ dinv,
                                                  int N, int NB, int E) {
    __shared__ int cnt[256];
    __shared__ int cur[256];
    __shared__ int wsum[4];
    const int b = blockIdx.x, t = threadIdx.x;
    const int start = bbase[b];
    const int end = (b + 1 < NB) ? bbase[b + 1] : E;
    cnt[t] = 0;
    __syncthreads();
    for (int j = start + t; j < end; j += THREADS)
        atomicAdd(&cnt[pairs[j] >> 24], 1);
    __syncthreads();
    int deg = cnt[t];
    int lane = t & 63, w = t >> 6;
    int v = deg;
#pragma unroll
    for (int o = 1; o < 64; o <<= 1) {
        int u = __shfl_up(v, o);
        if (lane >= o) v += u;
    }
    if (lane == 63) wsum[w] = v;
    __syncthreads();
    int wadd = 0;
#pragma unroll
    for (int k = 0; k < 4; ++k) if (k < w) wadd += wsum[k];
    int pos = start + (v - deg) + wadd;
    cur[t] = pos;
    int node = (b << BSHIFT) + t;
    if (node < N) {
        row_ptr[node] = pos;
        dinv[node] = rsqrtf((float)(deg + 1));  // +1 self loop
    }
    if (b == NB - 1 && t == 0) row_ptr[N] = end;
    __syncthreads();
    for (int j = start + t; j < end; j += THREADS) {
        unsigned p = pairs[j];
        int r = atomicAdd(&cur[p >> 24], 1);
        csr_src[r] = (int)(p & 0xFFFFFFu);
    }
}

// ---------------- GEMM1 (MFMA): h1h = fp16(dinv[row] * (x @ W1)) ----------------
__global__ __launch_bounds__(THREADS) void k_gemm1(const float* __restrict__ x,
                                                   const float* __restrict__ W,
                                                   const float* __restrict__ dinv,
                                                   _Float16* __restrict__ h, int N) {
    __shared__ _Float16 xs[64][136];   // [row][k], +8 pad
    __shared__ _Float16 wsT[64][136];  // [col][k], transposed W1
    const int tid = threadIdx.x;
    const int brow = blockIdx.x * 64;
    for (int f = tid; f < 64 * 32; f += THREADS) {
        int r = f >> 5, c4 = (f & 31) << 2;
        int row = brow + r;
        float4 v = make_float4(0.f, 0.f, 0.f, 0.f);
        if (row < N) v = *(const float4*)&x[(size_t)row * 128 + c4];
        h4v hv;
        hv.x = (_Float16)v.x; hv.y = (_Float16)v.y;
        hv.z = (_Float16)v.z; hv.w = (_Float16)v.w;
        *(h4v*)&xs[r][c4] = hv;
    }
    for (int f = tid; f < 128 * 16; f += THREADS) {
        int k = f >> 4, n4 = (f & 15) << 2;
        float4 w = *(const float4*)&W[(size_t)k * 64 + n4];
        wsT[n4 + 0][k] = (_Float16)w.x;
        wsT[n4 + 1][k] = (_Float16)w.y;
        wsT[n4 + 2][k] = (_Float16)w.z;
        wsT[n4 + 3][k] = (_Float16)w.w;
    }
    __syncthreads();
    const int wv = tid >> 6, lane = tid & 63;
    const int fr = lane & 15;
    const int kg = lane >> 4;
    f32x4 acc[4];
    acc[0] = acc[1] = acc[2] = acc[3] = (f32x4){0.f, 0.f, 0.f, 0.f};
#pragma unroll
    for (int ks = 0; ks < 4; ++ks) {
        h8v a = *(const h8v*)&xs[(wv << 4) + fr][(kg << 3) + (ks << 5)];
#pragma unroll
        for (int c = 0; c < 4; ++c) {
            h8v b = *(const h8v*)&wsT[(c << 4) + fr][(kg << 3) + (ks << 5)];
            acc[c] = __builtin_amdgcn_mfma_f32_16x16x32_f16(a, b, acc[c], 0, 0, 0);
        }
    }
#pragma unroll
    for (int i = 0; i < 4; ++i) {
        int row = brow + (wv << 4) + (kg << 2) + i;
        if (row < N) {
            float dn = dinv[row];
#pragma unroll
            for (int c = 0; c < 4; ++c)
                h[(size_t)row * 64 + (c << 4) + fr] = (_Float16)(acc[c][i] * dn);
        }
    }
}

// ---------------- fused layer-1 agg + bias + ReLU + GEMM2 (group-per-node, unroll-4) ----------------
__global__ __launch_bounds__(THREADS) void k_agg1f(const int* __restrict__ row_ptr,
                                                   const int* __restrict__ csr,
                                                   const float* __restrict__ dinv,
                                                   const _Float16* __restrict__ hs,
                                                   const float* __restrict__ b1,
                                                   const float* __restrict__ W2,
                                                   _Float16* __restrict__ h2s, int N) {
    __shared__ float w2s[64][32];          // 8KB
    __shared__ float rowbuf[4][8][68];     // 8.5KB, padded
    __shared__ int rp_s[AGG_NODES + 1];
    __shared__ float dinv_s[AGG_NODES];
    __shared__ int csr_s[CSR_LDS];         // 6KB
    const int tid = threadIdx.x;
    for (int f = tid; f < 64 * 8; f += THREADS) {
        int k = f >> 3, c4 = (f & 7) << 2;
        *(float4*)&w2s[k][c4] = *(const float4*)&W2[(size_t)k * 32 + c4];
    }
    const int nbase = blockIdx.x * AGG_NODES;
    const int nend = min(nbase + AGG_NODES, N);
    const int ncnt = nend - nbase;
    if (tid <= ncnt) rp_s[tid] = row_ptr[nbase + tid];
    if (tid < ncnt) dinv_s[tid] = dinv[nbase + tid];
    __syncthreads();
    const int seg0 = rp_s[0];
    const int seglen = rp_s[ncnt] - seg0;
    const bool inlds = (seglen <= CSR_LDS);
    if (inlds)
        for (int t = tid; t < seglen; t += THREADS) csr_s[t] = nt_ld_i(&csr[seg0 + t]);
    __syncthreads();

    const int wv = tid >> 6, lane = tid & 63;
    const int g = lane >> 3, fl = lane & 7;
    const int fb = fl << 3;

    for (int c = 0; c < 2; ++c) {
        const int nloc = (wv << 4) + (c << 3) + g;
        const bool act = (nloc < ncnt);
        const int node = nbase + nloc;
        const int start = act ? rp_s[nloc] : 0;
        const int end = act ? rp_s[nloc + 1] : 0;
        h8v a0 = {0, 0, 0, 0, 0, 0, 0, 0};
        h8v a1 = a0, a2 = a0, a3 = a0;
        if (act) a0 = *(const h8v*)&hs[(size_t)node * 64 + fb];  // self row
        if (inlds) {
            int j = start - seg0;
            const int e_ = end - seg0;
            for (; j + 3 < e_; j += 4) {
                int s0 = csr_s[j], s1 = csr_s[j + 1], s2 = csr_s[j + 2], s3 = csr_s[j + 3];
                a0 += *(const h8v*)&hs[(size_t)s0 * 64 + fb];
                a1 += *(const h8v*)&hs[(size_t)s1 * 64 + fb];
                a2 += *(const h8v*)&hs[(size_t)s2 * 64 + fb];
                a3 += *(const h8v*)&hs[(size_t)s3 * 64 + fb];
            }
            int rem = e_ - j;
            if (rem > 0) a1 += *(const h8v*)&hs[(size_t)csr_s[j] * 64 + fb];
            if (rem > 1) a2 += *(const h8v*)&hs[(size_t)csr_s[j + 1] * 64 + fb];
            if (rem > 2) a3 += *(const h8v*)&hs[(size_t)csr_s[j + 2] * 64 + fb];
        } else {
            int j = start;
            for (; j + 3 < end; j += 4) {
                int s0 = nt_ld_i(&csr[j]), s1 = nt_ld_i(&csr[j + 1]);
                int s2 = nt_ld_i(&csr[j + 2]), s3 = nt_ld_i(&csr[j + 3]);
                a0 += *(const h8v*)&hs[(size_t)s0 * 64 + fb];
                a1 += *(const h8v*)&hs[(size_t)s1 * 64 + fb];
                a2 += *(const h8v*)&hs[(size_t)s2 * 64 + fb];
                a3 += *(const h8v*)&hs[(size_t)s3 * 64 + fb];
            }
            int rem = end - j;
            if (rem > 0) a1 += *(const h8v*)&hs[(size_t)nt_ld_i(&csr[j]) * 64 + fb];
            if (rem > 1) a2 += *(const h8v*)&hs[(size_t)nt_ld_i(&csr[j + 1]) * 64 + fb];
            if (rem > 2) a3 += *(const h8v*)&hs[(size_t)nt_ld_i(&csr[j + 2]) * 64 + fb];
        }
        if (act) {
            const float dn = dinv_s[nloc];
            float4 bb0 = *(const float4*)&b1[fb];
            float4 bb1 = *(const float4*)&b1[fb + 4];
            float4 r0, r1;
            r0.x = fmaxf(dn * (((float)a0[0] + (float)a1[0]) + ((float)a2[0] + (float)a3[0])) + bb0.x, 0.f);
            r0.y = fmaxf(dn * (((float)a0[1] + (float)a1[1]) + ((float)a2[1] + (float)a3[1])) + bb0.y, 0.f);
            r0.z = fmaxf(dn * (((float)a0[2] + (float)a1[2]) + ((float)a2[2] + (float)a3[2])) + bb0.z, 0.f);
            r0.w = fmaxf(dn * (((float)a0[3] + (float)a1[3]) + ((float)a2[3] + (float)a3[3])) + bb0.w, 0.f);
            r1.x = fmaxf(dn * (((float)a0[4] + (float)a1[4]) + ((float)a2[4] + (float)a3[4])) + bb1.x, 0.f);
            r1.y = fmaxf(dn * (((float)a0[5] + (float)a1[5]) + ((float)a2[5] + (float)a3[5])) + bb1.y, 0.f);
            r1.z = fmaxf(dn * (((float)a0[6] + (float)a1[6]) + ((float)a2[6] + (float)a3[6])) + bb1.z, 0.f);
            r1.w = fmaxf(dn * (((float)a0[7] + (float)a1[7]) + ((float)a2[7] + (float)a3[7])) + bb1.w, 0.f);
            *(float4*)&rowbuf[wv][g][fb] = r0;
            *(float4*)&rowbuf[wv][g][fb + 4] = r1;
        }
        // GEMM2 (vectorized): 4 cols/lane, K=64 in float4 steps
        if (act) {
            float c0 = 0.f, c1 = 0.f, c2 = 0.f, c3 = 0.f;
            const int cb = fl << 2;
#pragma unroll
            for (int k4 = 0; k4 < 64; k4 += 4) {
                float4 r = *(const float4*)&rowbuf[wv][g][k4];
                float4 w0 = *(const float4*)&w2s[k4 + 0][cb];
                float4 w1 = *(const float4*)&w2s[k4 + 1][cb];
                float4 w2 = *(const float4*)&w2s[k4 + 2][cb];
                float4 w3 = *(const float4*)&w2s[k4 + 3][cb];
                c0 += r.x * w0.x + r.y * w1.x + r.z * w2.x + r.w * w3.x;
                c1 += r.x * w0.y + r.y * w1.y + r.z * w2.y + r.w * w3.y;
                c2 += r.x * w0.z + r.y * w1.z + r.z * w2.z + r.w * w3.z;
                c3 += r.x * w0.w + r.y * w1.w + r.z * w2.w + r.w * w3.w;
            }
            const float dn = dinv_s[nloc];
            h4v hv;
            hv.x = (_Float16)(dn * c0);
            hv.y = (_Float16)(dn * c1);
            hv.z = (_Float16)(dn * c2);
            hv.w = (_Float16)(dn * c3);
            *(h4v*)&h2s[(size_t)node * 32 + (fl << 2)] = hv;
        }
    }
}

// ---------------- layer-2 agg (group-per-node, unroll-4): 16 groups x 4 lanes ----------------
__global__ __launch_bounds__(THREADS) void k_agg2(const int* __restrict__ row_ptr,
                                                  const int* __restrict__ csr,
                                                  const float* __restrict__ dinv,
                                                  const _Float16* __restrict__ hs,
                                                  const float* __restrict__ b2,
                                                  float* __restrict__ out, int N) {
    __shared__ int rp_s[AGG_NODES + 1];
    __shared__ float dinv_s[AGG_NODES];
    __shared__ int csr_s[CSR_LDS];
    const int tid = threadIdx.x;
    const int nbase = blockIdx.x * AGG_NODES;
    const int nend = min(nbase + AGG_NODES, N);
    const int ncnt = nend - nbase;
    if (tid <= ncnt) rp_s[tid] = row_ptr[nbase + tid];
    if (tid < ncnt) dinv_s[tid] = dinv[nbase + tid];
    __syncthreads();
    const int seg0 = rp_s[0];
    const int seglen = rp_s[ncnt] - seg0;
    const bool inlds = (seglen <= CSR_LDS);
    if (inlds)
        for (int t = tid; t < seglen; t += THREADS) csr_s[t] = nt_ld_i(&csr[seg0 + t]);
    __syncthreads();

    const int wv = tid >> 6, lane = tid & 63;
    const int g = lane >> 2, fl = lane & 3;
    const int fb = fl << 3;

    const int nloc = (wv << 4) + g;
    const bool act = (nloc < ncnt);
    const int node = nbase + nloc;
    const int start = act ? rp_s[nloc] : 0;
    const int end = act ? rp_s[nloc + 1] : 0;
    h8v a0 = {0, 0, 0, 0, 0, 0, 0, 0};
    h8v a1 = a0, a2 = a0, a3 = a0;
    if (act) a0 = *(const h8v*)&hs[(size_t)node * 32 + fb];  // self row
    if (inlds) {
        int j = start - seg0;
        const int e_ = end - seg0;
        for (; j + 3 < e_; j += 4) {
            int s0 = csr_s[j], s1 = csr_s[j + 1], s2 = csr_s[j + 2], s3 = csr_s[j + 3];
            a0 += *(const h8v*)&hs[(size_t)s0 * 32 + fb];
            a1 += *(const h8v*)&hs[(size_t)s1 * 32 + fb];
            a2 += *(const h8v*)&hs[(size_t)s2 * 32 + fb];
            a3 += *(const h8v*)&hs[(size_t)s3 * 32 + fb];
        }
        int rem = e_ - j;
        if (rem > 0) a1 += *(const h8v*)&hs[(size_t)csr_s[j] * 32 + fb];
        if (rem > 1) a2 += *(const h8v*)&hs[(size_t)csr_s[j + 1] * 32 + fb];
        if (rem > 2) a3 += *(const h8v*)&hs[(size_t)csr_s[j + 2] * 32 + fb];
    } else {
        int j = start;
        for (; j + 3 < end; j += 4) {
            int s0 = nt_ld_i(&csr[j]), s1 = nt_ld_i(&csr[j + 1]);
            int s2 = nt_ld_i(&csr[j + 2]), s3 = nt_ld_i(&csr[j + 3]);
            a0 += *(const h8v*)&hs[(size_t)s0 * 32 + fb];
            a1 += *(const h8v*)&hs[(size_t)s1 * 32 + fb];
            a2 += *(const h8v*)&hs[(size_t)s2 * 32 + fb];
            a3 += *(const h8v*)&hs[(size_t)s3 * 32 + fb];
        }
        int rem = end - j;
        if (rem > 0) a1 += *(const h8v*)&hs[(size_t)nt_ld_i(&csr[j]) * 32 + fb];
        if (rem > 1) a2 += *(const h8v*)&hs[(size_t)nt_ld_i(&csr[j + 1]) * 32 + fb];
        if (rem > 2) a3 += *(const h8v*)&hs[(size_t)nt_ld_i(&csr[j + 2]) * 32 + fb];
    }
    if (act) {
        const float dn = dinv_s[nloc];
        float4 bb0 = *(const float4*)&b2[fb];
        float4 bb1 = *(const float4*)&b2[fb + 4];
        float4 r0, r1;
        r0.x = dn * (((float)a0[0] + (float)a1[0]) + ((float)a2[0] + (float)a3[0])) + bb0.x;
        r0.y = dn * (((float)a0[1] + (float)a1[1]) + ((float)a2[1] + (float)a3[1])) + bb0.y;
        r0.z = dn * (((float)a0[2] + (float)a1[2]) + ((float)a2[2] + (float)a3[2])) + bb0.z;
        r0.w = dn * (((float)a0[3] + (float)a1[3]) + ((float)a2[3] + (float)a3[3])) + bb0.w;
        r1.x = dn * (((float)a0[4] + (float)a1[4]) + ((float)a2[4] + (float)a3[4])) + bb1.x;
        r1.y = dn * (((float)a0[5] + (float)a1[5]) + ((float)a2[5] + (float)a3[5])) + bb1.y;
        r1.z = dn * (((float)a0[6] + (float)a1[6]) + ((float)a2[6] + (float)a3[6])) + bb1.z;
        r1.w = dn * (((float)a0[7] + (float)a1[7]) + ((float)a2[7] + (float)a3[7])) + bb1.w;
        *(float4*)&out[(size_t)node * 32 + fb] = r0;
        *(float4*)&out[(size_t)node * 32 + fb + 4] = r1;
    }
}

extern "C" void kernel_launch(void* const* d_in, const int* in_sizes, int n_in,
                              void* d_out, int out_size, void* d_ws, size_t ws_size,
                              hipStream_t stream) {
    const int N = in_sizes[0] / 128;
    const int E = in_sizes[1] / 2;
    const float* x  = (const float*)d_in[0];
    const int*   ei = (const int*)d_in[1];
    const float* W1 = (const float*)d_in[2];
    const float* b1 = (const float*)d_in[3];
    const float* W2 = (const float*)d_in[4];
    const float* b2 = (const float*)d_in[5];
    float* out = (float*)d_out;

    const int NB = (N + 255) >> BSHIFT;

    // workspace carve. pairs aliases h1b (dead until k_gemm1, which runs after k_sort;
    // E*4B = 6.4MB <= N*64*2B = 12.8MB).
    float*     dinv    = (float*)d_ws;                    // N
    _Float16*  h1b     = (_Float16*)(dinv + N);           // N*64 fp16
    _Float16*  h2b     = h1b + (size_t)N * 64;            // N*32 fp16
    int*       csr_src = (int*)(h2b + (size_t)N * 32);    // E
    int*       row_ptr = csr_src + E;                     // N+1
    int*       bh      = row_ptr + N + 1;                 // PBLK*NB
    int*       bbase   = bh + (size_t)PBLK * NB;          // PBLK*NB
    int*       bcnt    = bbase + (size_t)PBLK * NB;       // NB
    unsigned*  pairs   = (unsigned*)h1b;                  // E (aliased)

    k_hist<<<PBLK, HTHREADS, (NB + 1) * 4, stream>>>(ei, E, bh, NB);
    k_colsum<<<NB, THREADS, 0, stream>>>(bh, bcnt, NB);
    k_bbase<<<NB, 64, 0, stream>>>(bh, bcnt, bbase, NB);
    k_partition<<<PBLK, HTHREADS, (2 * NB + 1) * 4, stream>>>(ei, E, bbase, pairs, NB);
    k_sort<<<NB, THREADS, 0, stream>>>(pairs, bbase, csr_src, row_ptr, dinv, N, NB, E);

    k_gemm1<<<(N + 63) / 64, THREADS, 0, stream>>>(x, W1, dinv, h1b, N);
    const int ablk = (N + AGG_NODES - 1) / AGG_NODES;
    k_agg1f<<<ablk, THREADS, 0, stream>>>(row_ptr, csr_src, dinv, h1b, b1, W2, h2b, N);
    k_agg2<<<ablk, THREADS, 0, stream>>>(row_ptr, csr_src, dinv, h2b, b2, out, N);
}